// Round 1
// baseline (22769.127 us; speedup 1.0000x reference)
//
#include <hip/hip_runtime.h>
#include <hip/hip_bf16.h>

#define NL 12
#define Dm 768
#define NH 12
#define HD 64
#define NV 50257
#define NB 2
#define NT 1024
#define MROWS (NB * NT)   // 2048

// ---------------------------------------------------------------- embedding
__global__ void embed_kernel(const int* __restrict__ ids,
                             const float* __restrict__ wte,
                             const float* __restrict__ wpe,
                             float* __restrict__ x) {
    int row = blockIdx.x;            // 0..2047 = b*NT + t
    int t = row & (NT - 1);
    int id = ids[row];
    const float* src = wte + (size_t)id * Dm;
    const float* pos = wpe + (size_t)t * Dm;
    float* dst = x + (size_t)row * Dm;
    for (int i = threadIdx.x; i < Dm; i += 256)
        dst[i] = src[i] + pos[i];
}

// ---------------------------------------------------------------- layernorm
// one block (256 threads) per row of 768
__global__ void ln_kernel(const float* __restrict__ x,
                          const float* __restrict__ g,
                          const float* __restrict__ b,
                          float* __restrict__ out) {
    int row = blockIdx.x;
    int tid = threadIdx.x;
    const float* xr = x + (size_t)row * Dm;
    float v0 = xr[tid];
    float v1 = xr[tid + 256];
    float v2 = xr[tid + 512];
    float s = v0 + v1 + v2;
    #pragma unroll
    for (int off = 32; off; off >>= 1) s += __shfl_xor(s, off);
    __shared__ float red[4];
    __shared__ float red2[4];
    int wid = tid >> 6;
    if ((tid & 63) == 0) red[wid] = s;
    __syncthreads();
    float mean = (red[0] + red[1] + red[2] + red[3]) * (1.0f / Dm);
    float d0 = v0 - mean, d1 = v1 - mean, d2 = v2 - mean;
    float sq = d0 * d0 + d1 * d1 + d2 * d2;
    #pragma unroll
    for (int off = 32; off; off >>= 1) sq += __shfl_xor(sq, off);
    if ((tid & 63) == 0) red2[wid] = sq;
    __syncthreads();
    float var = (red2[0] + red2[1] + red2[2] + red2[3]) * (1.0f / Dm);
    float rstd = rsqrtf(var + 1e-5f);
    float* o = out + (size_t)row * Dm;
    o[tid]       = d0 * rstd * g[tid]       + b[tid];
    o[tid + 256] = d1 * rstd * g[tid + 256] + b[tid + 256];
    o[tid + 512] = d2 * rstd * g[tid + 512] + b[tid + 512];
}

// ---------------------------------------------------------------- GEMM
// C[M,N] = act(A[M,K] @ W + bias) + resid
// TRANSB=false: W is [K,N] row-major.  TRANSB=true: W is [N,K] row-major.
// Block: 256 threads, tile 64x64, BK=16, 4x4 per thread.
// M % 64 == 0 and K % 16 == 0 always hold here; N guarded (lm-head N=50257).
#define BM 64
#define BN 64
#define BK 16

__device__ __forceinline__ float gelu_exact(float v) {
    return 0.5f * v * (1.0f + erff(v * 0.70710678118654752f));
}

template <bool TRANSB>
__global__ void gemm_kernel(const float* __restrict__ A,
                            const float* __restrict__ W,
                            const float* __restrict__ bias,
                            const float* __restrict__ resid,
                            float* __restrict__ C,
                            int M, int K, int N, int act) {
    __shared__ float As[BK][BM + 1];   // [kk][m]
    __shared__ float Bs[BK][BN];       // [kk][n]
    int tid = threadIdx.x;
    int tx = tid & 15, ty = tid >> 4;
    int m0 = blockIdx.y * BM;
    int n0 = blockIdx.x * BN;

    float acc[4][4] = {};

    int am = tid >> 2, ak4 = (tid & 3) << 2;       // A staging: 64x16 chunk
    for (int k0 = 0; k0 < K; k0 += BK) {
        float4 a4 = *(const float4*)(A + (size_t)(m0 + am) * K + k0 + ak4);
        As[ak4 + 0][am] = a4.x;
        As[ak4 + 1][am] = a4.y;
        As[ak4 + 2][am] = a4.z;
        As[ak4 + 3][am] = a4.w;
        if (!TRANSB) {
            int bk = tid >> 4, bn4 = (tid & 15) << 2;
            float4 b4 = *(const float4*)(W + (size_t)(k0 + bk) * N + n0 + bn4);
            *(float4*)&Bs[bk][bn4] = b4;
        } else {
            int bn = tid >> 2, bk4 = (tid & 3) << 2;
            float4 b4 = make_float4(0.f, 0.f, 0.f, 0.f);
            if (n0 + bn < N)
                b4 = *(const float4*)(W + (size_t)(n0 + bn) * K + k0 + bk4);
            Bs[bk4 + 0][bn] = b4.x;
            Bs[bk4 + 1][bn] = b4.y;
            Bs[bk4 + 2][bn] = b4.z;
            Bs[bk4 + 3][bn] = b4.w;
        }
        __syncthreads();
        #pragma unroll
        for (int kk = 0; kk < BK; ++kk) {
            float a0 = As[kk][ty * 4 + 0];
            float a1 = As[kk][ty * 4 + 1];
            float a2 = As[kk][ty * 4 + 2];
            float a3 = As[kk][ty * 4 + 3];
            float b0 = Bs[kk][tx * 4 + 0];
            float b1 = Bs[kk][tx * 4 + 1];
            float b2 = Bs[kk][tx * 4 + 2];
            float b3 = Bs[kk][tx * 4 + 3];
            acc[0][0] += a0 * b0; acc[0][1] += a0 * b1; acc[0][2] += a0 * b2; acc[0][3] += a0 * b3;
            acc[1][0] += a1 * b0; acc[1][1] += a1 * b1; acc[1][2] += a1 * b2; acc[1][3] += a1 * b3;
            acc[2][0] += a2 * b0; acc[2][1] += a2 * b1; acc[2][2] += a2 * b2; acc[2][3] += a2 * b3;
            acc[3][0] += a3 * b0; acc[3][1] += a3 * b1; acc[3][2] += a3 * b2; acc[3][3] += a3 * b3;
        }
        __syncthreads();
    }

    #pragma unroll
    for (int i = 0; i < 4; ++i) {
        int r = m0 + ty * 4 + i;
        float* crow = C + (size_t)r * N;
        const float* rrow = resid ? resid + (size_t)r * N : nullptr;
        #pragma unroll
        for (int j = 0; j < 4; ++j) {
            int c = n0 + tx * 4 + j;
            if (c < N) {
                float v = acc[i][j];
                if (bias) v += bias[c];
                if (act)  v = gelu_exact(v);
                if (rrow) v += rrow[c];
                crow[c] = v;
            }
        }
    }
}

// ---------------------------------------------------------------- attention
// One wave (64 lanes) per query row; lane d holds head-dim d. Online softmax.
// qkv layout: [B*NT][3*Dm], q at col h*64+d, k at 768+..., v at 1536+...
__global__ void attn_kernel(const float* __restrict__ qkv,
                            float* __restrict__ y) {
    int gw = blockIdx.x * 4 + (threadIdx.x >> 6);   // global wave id 0..24575
    int lane = threadIdx.x & 63;
    int q = gw & (NT - 1);
    int bh = gw >> 10;
    int h = bh % NH;
    int b = bh / NH;

    const float scale = 0.125f;  // 1/sqrt(64)
    const float* base = qkv + (size_t)b * NT * (3 * Dm);
    int col = h * HD + lane;

    float qv = base[(size_t)q * (3 * Dm) + col] * scale;
    float m = -1e30f, l = 0.0f, acc = 0.0f;
    for (int k = 0; k <= q; ++k) {
        const float* krow = base + (size_t)k * (3 * Dm);
        float kv = krow[Dm + col];
        float s = qv * kv;
        #pragma unroll
        for (int off = 32; off; off >>= 1) s += __shfl_xor(s, off);
        float mn = fmaxf(m, s);
        float alpha = __expf(m - mn);
        float p = __expf(s - mn);
        float vv = krow[2 * Dm + col];
        l = l * alpha + p;
        acc = acc * alpha + p * vv;
        m = mn;
    }
    y[(size_t)(b * NT + q) * Dm + col] = acc / l;
}

// ---------------------------------------------------------------- launch
extern "C" void kernel_launch(void* const* d_in, const int* in_sizes, int n_in,
                              void* d_out, int out_size, void* d_ws, size_t ws_size,
                              hipStream_t stream) {
    const int*   ids    = (const int*)  d_in[0];
    const float* wte    = (const float*)d_in[1];
    const float* wpe    = (const float*)d_in[2];
    const float* ln1_g  = (const float*)d_in[3];
    const float* ln1_b  = (const float*)d_in[4];
    const float* attn_w = (const float*)d_in[5];
    const float* attn_b = (const float*)d_in[6];
    const float* proj_w = (const float*)d_in[7];
    const float* proj_b = (const float*)d_in[8];
    const float* ln2_g  = (const float*)d_in[9];
    const float* ln2_b  = (const float*)d_in[10];
    const float* fc_w   = (const float*)d_in[11];
    const float* fc_b   = (const float*)d_in[12];
    const float* fc2_w  = (const float*)d_in[13];
    const float* fc2_b  = (const float*)d_in[14];
    const float* lnf_g  = (const float*)d_in[15];
    const float* lnf_b  = (const float*)d_in[16];
    float* out = (float*)d_out;

    float* ws  = (float*)d_ws;
    float* x   = ws;                         // [2048][768]
    float* h   = x   + (size_t)MROWS * Dm;   // [2048][768]
    float* qkv = h   + (size_t)MROWS * Dm;   // [2048][2304]
    float* y   = qkv + (size_t)MROWS * 3 * Dm; // [2048][768]
    float* h4  = y   + (size_t)MROWS * Dm;   // [2048][3072]

    embed_kernel<<<MROWS, 256, 0, stream>>>(ids, wte, wpe, x);

    for (int l = 0; l < NL; ++l) {
        ln_kernel<<<MROWS, 256, 0, stream>>>(x, ln1_g + l * Dm, ln1_b + l * Dm, h);
        gemm_kernel<false><<<dim3(3 * Dm / BN, MROWS / BM), 256, 0, stream>>>(
            h, attn_w + (size_t)l * Dm * 3 * Dm, attn_b + (size_t)l * 3 * Dm,
            nullptr, qkv, MROWS, Dm, 3 * Dm, 0);
        attn_kernel<<<(NB * NH * NT) / 4, 256, 0, stream>>>(qkv, y);
        gemm_kernel<false><<<dim3(Dm / BN, MROWS / BM), 256, 0, stream>>>(
            y, proj_w + (size_t)l * Dm * Dm, proj_b + (size_t)l * Dm,
            x, x, MROWS, Dm, Dm, 0);
        ln_kernel<<<MROWS, 256, 0, stream>>>(x, ln2_g + l * Dm, ln2_b + l * Dm, h);
        gemm_kernel<false><<<dim3(4 * Dm / BN, MROWS / BM), 256, 0, stream>>>(
            h, fc_w + (size_t)l * Dm * 4 * Dm, fc_b + (size_t)l * 4 * Dm,
            nullptr, h4, MROWS, Dm, 4 * Dm, 1);
        gemm_kernel<false><<<dim3(Dm / BN, MROWS / BM), 256, 0, stream>>>(
            h4, fc2_w + (size_t)l * 4 * Dm * Dm, fc2_b + (size_t)l * Dm,
            x, x, MROWS, 4 * Dm, Dm, 0);
    }

    ln_kernel<<<MROWS, 256, 0, stream>>>(x, lnf_g, lnf_b, h);
    gemm_kernel<true><<<dim3((NV + BN - 1) / BN, MROWS / BM), 256, 0, stream>>>(
        h, wte, nullptr, nullptr, out, MROWS, Dm, NV, 0);
}